// Round 1
// baseline (994.726 us; speedup 1.0000x reference)
//
#include <hip/hip_runtime.h>

// MEGNet edge conv, latency-optimized, operand-swapped MFMA:
//  All GEMMs compute (X·W)^T via mfma(Wfrag, Xfrag) so each lane's C-fragment
//  holds 4 CONTIGUOUS features of ONE edge row -> direct packed global stores.
//  This eliminates the per-subtile LDS transpose round-trip (ds_write_b16 x16 +
//  threadfence + ds_read_b128) that serialized every tile, and drops K1 LDS
//  42.5->32.8 KB (3 -> 4 blocks/CU).
//  prep : W1 -> MFMA-fragment-order bf16 + zero stats (fragments unchanged:
//         A-operand layout (row=lane&15, k=quad*8+j) is bit-identical to the
//         old B-operand layout (col=lane&15, k=quad*8+j)).
//  K1   : gather-concat GEMM [E,256]@[256,64], loads hoisted, batch prefetch,
//         direct 8B bf16 stores, per-feature stats via shfl_xor(1,2,4,8)
//  K2   : fold BN1 into W2; [E,64]@[64,64]; h2 bf16; stats2
//  K3   : fold BN2 into W3; stats-only pass over h2 -> stats3
//  K4   : fold BN2 into W3 + BN3 affine; recompute GEMM3; store fp32 out

typedef unsigned short u16;
typedef unsigned int u32;
using bf16x8 = __bf16 __attribute__((ext_vector_type(8)));
using f32x4  = float __attribute__((ext_vector_type(4)));
using u32x2  = u32 __attribute__((ext_vector_type(2)));
using u32x4  = u32 __attribute__((ext_vector_type(4)));

#define BN_EPS 1e-5f

__device__ __forceinline__ u16 f2bf(float f) {
    u32 u = __builtin_bit_cast(u32, f);
    u += 0x7fffu + ((u >> 16) & 1u);   // RNE (finite inputs)
    return (u16)(u >> 16);
}
__device__ __forceinline__ u32 pk2(float a, float b) {
    return (u32)f2bf(a) | ((u32)f2bf(b) << 16);
}

// ---- prep: W1 -> fragment-order bf16; zero the 384 stats floats
__global__ __launch_bounds__(256) void prep_kernel(const float* __restrict__ W1,
                                                   u16* __restrict__ w1f,
                                                   float* __restrict__ statsz) {
    int t = blockIdx.x * 256 + threadIdx.x;
    if (t < 16384) {
        int j = t & 7, lane = (t >> 3) & 63, fa = (t >> 9) & 3, s = (t >> 11) & 1, c = t >> 12;
        int m = lane & 15, quad = lane >> 4;
        int k = c * 64 + s * 32 + quad * 8 + j;
        int n = fa * 16 + m;
        w1f[t] = f2bf(W1[k * 64 + n]);
    }
    if (t < 384) statsz[t] = 0.0f;
}

// ---- K1: concat GEMM, K=256; loads fully hoisted; direct-store epilogue
__global__ __launch_bounds__(256) void gemm1_kernel(
    const float* __restrict__ src, const float* __restrict__ dst,
    const float* __restrict__ edg, const float* __restrict__ gat,
    const int* __restrict__ batch, const u16* __restrict__ w1f,
    const float* __restrict__ b1, u16* __restrict__ Y,
    float* __restrict__ stats, int tiles)
{
    __shared__ u16 sW[16384];         // fragment-order W1 (32 KB)
    __shared__ float sSum[64], sSq[64];
    const int tid = threadIdx.x;
    {
        const u32x4* g = (const u32x4*)w1f;
        u32x4* l = (u32x4*)sW;
        #pragma unroll
        for (int i = 0; i < 8; i++) l[tid + i * 256] = g[tid + i * 256];
    }
    if (tid < 64) { sSum[tid] = 0.f; sSq[tid] = 0.f; }
    __syncthreads();

    const int wave = tid >> 6, lane = tid & 63;
    const int m = lane & 15, quad = lane >> 4;
    const u32x4* sWv = (const u32x4*)sW;

    // per-lane features: fa*16 + quad*4 + r
    f32x4 bias4[4];
    #pragma unroll
    for (int fa = 0; fa < 4; fa++) bias4[fa] = *(const f32x4*)(b1 + fa * 16 + quad * 4);
    f32x4 ssum4[4] = {{0,0,0,0},{0,0,0,0},{0,0,0,0},{0,0,0,0}};
    f32x4 ssq4[4]  = {{0,0,0,0},{0,0,0,0},{0,0,0,0},{0,0,0,0}};

    const int gs = gridDim.x;
    const int rowoff = wave * 16 + m;
    int t = blockIdx.x;
    int bi = (t < tiles) ? batch[(size_t)t * 64 + rowoff] : 0;

    for (; t < tiles; t += gs) {
        const size_t rbase = (size_t)t * 64 + wave * 16;
        float4 L[16];
        {
            const float* p0 = src + (rbase + m) * 64 + quad * 8;
            const float* p1 = dst + (rbase + m) * 64 + quad * 8;
            const float* p2 = edg + (rbase + m) * 64 + quad * 8;
            const float* p3 = gat + (size_t)bi * 64 + quad * 8;
            L[0]  = *(const float4*)(p0);      L[1]  = *(const float4*)(p0 + 4);
            L[2]  = *(const float4*)(p0 + 32); L[3]  = *(const float4*)(p0 + 36);
            L[4]  = *(const float4*)(p1);      L[5]  = *(const float4*)(p1 + 4);
            L[6]  = *(const float4*)(p1 + 32); L[7]  = *(const float4*)(p1 + 36);
            L[8]  = *(const float4*)(p2);      L[9]  = *(const float4*)(p2 + 4);
            L[10] = *(const float4*)(p2 + 32); L[11] = *(const float4*)(p2 + 36);
            L[12] = *(const float4*)(p3);      L[13] = *(const float4*)(p3 + 4);
            L[14] = *(const float4*)(p3 + 32); L[15] = *(const float4*)(p3 + 36);
        }
        int tn = t + gs;
        int bn = (tn < tiles) ? batch[(size_t)tn * 64 + rowoff] : 0;

        f32x4 acc[4] = {{0,0,0,0},{0,0,0,0},{0,0,0,0},{0,0,0,0}};
        #pragma unroll
        for (int c = 0; c < 4; c++) {
            #pragma unroll
            for (int s = 0; s < 2; s++) {
                float4 f0 = L[c * 4 + s * 2], f1 = L[c * 4 + s * 2 + 1];
                u32x4 av = { pk2(f0.x, f0.y), pk2(f0.z, f0.w),
                             pk2(f1.x, f1.y), pk2(f1.z, f1.w) };
                bf16x8 xv = __builtin_bit_cast(bf16x8, av);
                #pragma unroll
                for (int fa = 0; fa < 4; fa++) {
                    bf16x8 wf = __builtin_bit_cast(bf16x8, sWv[((c * 2 + s) * 4 + fa) * 64 + lane]);
                    // swapped: D = W^T · X^T = (X·W)^T -> col=edge(lane&15), row=feature
                    acc[fa] = __builtin_amdgcn_mfma_f32_16x16x32_bf16(wf, xv, acc[fa], 0, 0, 0);
                }
            }
        }
        u16* yrow = Y + (rbase + m) * 64;
        #pragma unroll
        for (int fa = 0; fa < 4; fa++) {
            f32x4 x;
            #pragma unroll
            for (int r = 0; r < 4; r++) x[r] = fmaxf(acc[fa][r] + bias4[fa][r], 0.f);
            ssum4[fa] += x;
            #pragma unroll
            for (int r = 0; r < 4; r++) ssq4[fa][r] = fmaf(x[r], x[r], ssq4[fa][r]);
            u32x2 pv = { pk2(x[0], x[1]), pk2(x[2], x[3]) };
            *(u32x2*)(yrow + fa * 16 + quad * 4) = pv;   // 8B direct store
        }
        bi = bn;
    }
    // stats: reduce across the 16 m-lanes (feature is (fa,quad,r)-indexed)
    #pragma unroll
    for (int fa = 0; fa < 4; fa++) {
        #pragma unroll
        for (int r = 0; r < 4; r++) {
            float s = ssum4[fa][r], q = ssq4[fa][r];
            s += __shfl_xor(s, 1); s += __shfl_xor(s, 2); s += __shfl_xor(s, 4); s += __shfl_xor(s, 8);
            q += __shfl_xor(q, 1); q += __shfl_xor(q, 2); q += __shfl_xor(q, 4); q += __shfl_xor(q, 8);
            if (m == 0) {
                atomicAdd(&sSum[fa * 16 + quad * 4 + r], s);
                atomicAdd(&sSq [fa * 16 + quad * 4 + r], q);
            }
        }
    }
    __syncthreads();
    if (tid < 64) { atomicAdd(&stats[tid], sSum[tid]); atomicAdd(&stats[64 + tid], sSq[tid]); }
}

// ---- shared preamble: fold BN(stats_in,g,be) into W,b -> per-lane fragments
// Produces Wf[s][fa] (first-operand fragments, bf16) and bias4[fa] (f32x4,
// features fa*16+quad*4+r) in registers.
#define FOLD_PREAMBLE(STATS, G, BE, W, B)                                      \
    for (int i = tid; i < 1024; i += 256)                                      \
        ((float4*)sWf)[i] = ((const float4*)(W))[i];                           \
    if (tid < 64) {                                                            \
        float mean = (STATS)[tid] * invE;                                      \
        float var  = (STATS)[64 + tid] * invE - mean * mean;                   \
        float a = (G)[tid] / sqrtf(var + BN_EPS);                              \
        sAc[tid] = a; sCc[tid] = (BE)[tid] - mean * a;                         \
        sSum[tid] = 0.f; sSq[tid] = 0.f;                                       \
    }                                                                          \
    __syncthreads();                                                           \
    if (tid < 64) {                                                            \
        float bacc = (B)[tid];                                                 \
        for (int k = 0; k < 64; k++) bacc = fmaf(sCc[k], sWf[k * 64 + tid], bacc); \
        sBp[tid] = bacc;                                                       \
    }                                                                          \
    __syncthreads();                                                           \
    bf16x8 Wf[2][4];                                                           \
    f32x4 bias4[4];                                                            \
    {                                                                          \
        _Pragma("unroll")                                                      \
        for (int s = 0; s < 2; s++) {                                          \
            _Pragma("unroll")                                                  \
            for (int fa = 0; fa < 4; fa++) {                                   \
                int n = fa * 16 + m;                                           \
                u32x4 wv;                                                      \
                _Pragma("unroll")                                              \
                for (int jj = 0; jj < 4; jj++) {                               \
                    int k = s * 32 + quad * 8 + jj * 2;                        \
                    wv[jj] = pk2(sAc[k] * sWf[k * 64 + n],                     \
                                 sAc[k + 1] * sWf[(k + 1) * 64 + n]);          \
                }                                                              \
                Wf[s][fa] = __builtin_bit_cast(bf16x8, wv);                    \
            }                                                                  \
        }                                                                      \
        _Pragma("unroll")                                                      \
        for (int fa = 0; fa < 4; fa++)                                         \
            bias4[fa] = *(const f32x4*)&sBp[fa * 16 + quad * 4];               \
    }

// ---- K2: fold(BN1)->W2; GEMM; store h2 bf16 (direct); stats2
__global__ __launch_bounds__(256) void gemm_mid_kernel(
    const u16* __restrict__ X, const float* __restrict__ W, const float* __restrict__ b,
    const float* __restrict__ stats_in, float invE,
    const float* __restrict__ g, const float* __restrict__ be,
    u16* __restrict__ Y, float* __restrict__ stats_out, int tiles)
{
    __shared__ float sWf[4096];
    __shared__ float sAc[64], sCc[64], sBp[64];
    __shared__ float sSum[64], sSq[64];
    const int tid = threadIdx.x;
    const int wave = tid >> 6, lane = tid & 63;
    const int m = lane & 15, quad = lane >> 4;

    FOLD_PREAMBLE(stats_in, g, be, W, b)

    f32x4 ssum4[4] = {{0,0,0,0},{0,0,0,0},{0,0,0,0},{0,0,0,0}};
    f32x4 ssq4[4]  = {{0,0,0,0},{0,0,0,0},{0,0,0,0},{0,0,0,0}};
    const int nw = gridDim.x * 4;
    for (int t = blockIdx.x * 4 + wave; t < tiles; t += nw) {
        u32x4 Xf[8];
        const u16* xb = X + (size_t)t * 4096 + m * 64 + quad * 8;
        #pragma unroll
        for (int u = 0; u < 4; u++) {
            Xf[u * 2]     = *(const u32x4*)(xb + u * 1024);
            Xf[u * 2 + 1] = *(const u32x4*)(xb + u * 1024 + 32);
        }
        #pragma unroll
        for (int u = 0; u < 4; u++) {
            f32x4 acc[4] = {{0,0,0,0},{0,0,0,0},{0,0,0,0},{0,0,0,0}};
            #pragma unroll
            for (int s = 0; s < 2; s++) {
                bf16x8 xv = __builtin_bit_cast(bf16x8, Xf[u * 2 + s]);
                #pragma unroll
                for (int fa = 0; fa < 4; fa++)
                    acc[fa] = __builtin_amdgcn_mfma_f32_16x16x32_bf16(Wf[s][fa], xv, acc[fa], 0, 0, 0);
            }
            u16* yrow = Y + (size_t)t * 4096 + (u * 16 + m) * 64;
            #pragma unroll
            for (int fa = 0; fa < 4; fa++) {
                f32x4 x;
                #pragma unroll
                for (int r = 0; r < 4; r++) x[r] = fmaxf(acc[fa][r] + bias4[fa][r], 0.f);
                ssum4[fa] += x;
                #pragma unroll
                for (int r = 0; r < 4; r++) ssq4[fa][r] = fmaf(x[r], x[r], ssq4[fa][r]);
                u32x2 pv = { pk2(x[0], x[1]), pk2(x[2], x[3]) };
                *(u32x2*)(yrow + fa * 16 + quad * 4) = pv;
            }
        }
    }
    #pragma unroll
    for (int fa = 0; fa < 4; fa++) {
        #pragma unroll
        for (int r = 0; r < 4; r++) {
            float s = ssum4[fa][r], q = ssq4[fa][r];
            s += __shfl_xor(s, 1); s += __shfl_xor(s, 2); s += __shfl_xor(s, 4); s += __shfl_xor(s, 8);
            q += __shfl_xor(q, 1); q += __shfl_xor(q, 2); q += __shfl_xor(q, 4); q += __shfl_xor(q, 8);
            if (m == 0) {
                atomicAdd(&sSum[fa * 16 + quad * 4 + r], s);
                atomicAdd(&sSq [fa * 16 + quad * 4 + r], q);
            }
        }
    }
    __syncthreads();
    if (tid < 64) { atomicAdd(&stats_out[tid], sSum[tid]); atomicAdd(&stats_out[64 + tid], sSq[tid]); }
}

// ---- K3: fold(BN2)->W3; stats-only pass over h2 (no stores)
__global__ __launch_bounds__(256) void gemm_stats_kernel(
    const u16* __restrict__ X, const float* __restrict__ W, const float* __restrict__ b,
    const float* __restrict__ stats_in, float invE,
    const float* __restrict__ g, const float* __restrict__ be,
    float* __restrict__ stats_out, int tiles)
{
    __shared__ float sWf[4096];
    __shared__ float sAc[64], sCc[64], sBp[64];
    __shared__ float sSum[64], sSq[64];
    const int tid = threadIdx.x;
    const int wave = tid >> 6, lane = tid & 63;
    const int m = lane & 15, quad = lane >> 4;

    FOLD_PREAMBLE(stats_in, g, be, W, b)

    f32x4 ssum4[4] = {{0,0,0,0},{0,0,0,0},{0,0,0,0},{0,0,0,0}};
    f32x4 ssq4[4]  = {{0,0,0,0},{0,0,0,0},{0,0,0,0},{0,0,0,0}};
    const int nw = gridDim.x * 4;
    for (int t = blockIdx.x * 4 + wave; t < tiles; t += nw) {
        u32x4 Xf[8];
        const u16* xb = X + (size_t)t * 4096 + m * 64 + quad * 8;
        #pragma unroll
        for (int u = 0; u < 4; u++) {
            Xf[u * 2]     = *(const u32x4*)(xb + u * 1024);
            Xf[u * 2 + 1] = *(const u32x4*)(xb + u * 1024 + 32);
        }
        #pragma unroll
        for (int u = 0; u < 4; u++) {
            f32x4 acc[4] = {{0,0,0,0},{0,0,0,0},{0,0,0,0},{0,0,0,0}};
            #pragma unroll
            for (int s = 0; s < 2; s++) {
                bf16x8 xv = __builtin_bit_cast(bf16x8, Xf[u * 2 + s]);
                #pragma unroll
                for (int fa = 0; fa < 4; fa++)
                    acc[fa] = __builtin_amdgcn_mfma_f32_16x16x32_bf16(Wf[s][fa], xv, acc[fa], 0, 0, 0);
            }
            #pragma unroll
            for (int fa = 0; fa < 4; fa++) {
                f32x4 x;
                #pragma unroll
                for (int r = 0; r < 4; r++) x[r] = fmaxf(acc[fa][r] + bias4[fa][r], 0.f);
                ssum4[fa] += x;
                #pragma unroll
                for (int r = 0; r < 4; r++) ssq4[fa][r] = fmaf(x[r], x[r], ssq4[fa][r]);
            }
        }
    }
    #pragma unroll
    for (int fa = 0; fa < 4; fa++) {
        #pragma unroll
        for (int r = 0; r < 4; r++) {
            float s = ssum4[fa][r], q = ssq4[fa][r];
            s += __shfl_xor(s, 1); s += __shfl_xor(s, 2); s += __shfl_xor(s, 4); s += __shfl_xor(s, 8);
            q += __shfl_xor(q, 1); q += __shfl_xor(q, 2); q += __shfl_xor(q, 4); q += __shfl_xor(q, 8);
            if (m == 0) {
                atomicAdd(&sSum[fa * 16 + quad * 4 + r], s);
                atomicAdd(&sSq [fa * 16 + quad * 4 + r], q);
            }
        }
    }
    __syncthreads();
    if (tid < 64) { atomicAdd(&stats_out[tid], sSum[tid]); atomicAdd(&stats_out[64 + tid], sSq[tid]); }
}

// ---- K4: fold(BN2)->W3 + BN3 affine; recompute GEMM3; store fp32 out direct
__global__ __launch_bounds__(256) void gemm_out_kernel(
    const u16* __restrict__ X, const float* __restrict__ W, const float* __restrict__ b,
    const float* __restrict__ stats_in, float invE,
    const float* __restrict__ g, const float* __restrict__ be,
    const float* __restrict__ stats3, const float* __restrict__ g3,
    const float* __restrict__ be3, float* __restrict__ out, int tiles)
{
    __shared__ float sWf[4096];
    __shared__ float sAc[64], sCc[64], sBp[64];
    __shared__ float sSum[64], sSq[64];
    __shared__ float sA3[64], sC3[64];
    const int tid = threadIdx.x;
    const int wave = tid >> 6, lane = tid & 63;
    const int m = lane & 15, quad = lane >> 4;

    if (tid < 64) {
        float mean = stats3[tid] * invE;
        float var  = stats3[64 + tid] * invE - mean * mean;
        float a = g3[tid] / sqrtf(var + BN_EPS);
        sA3[tid] = a; sC3[tid] = be3[tid] - mean * a;
    }
    FOLD_PREAMBLE(stats_in, g, be, W, b)

    f32x4 a34[4], c34[4];
    #pragma unroll
    for (int fa = 0; fa < 4; fa++) {
        a34[fa] = *(const f32x4*)&sA3[fa * 16 + quad * 4];
        c34[fa] = *(const f32x4*)&sC3[fa * 16 + quad * 4];
    }

    const int nw = gridDim.x * 4;
    for (int t = blockIdx.x * 4 + wave; t < tiles; t += nw) {
        u32x4 Xf[8];
        const u16* xb = X + (size_t)t * 4096 + m * 64 + quad * 8;
        #pragma unroll
        for (int u = 0; u < 4; u++) {
            Xf[u * 2]     = *(const u32x4*)(xb + u * 1024);
            Xf[u * 2 + 1] = *(const u32x4*)(xb + u * 1024 + 32);
        }
        #pragma unroll
        for (int u = 0; u < 4; u++) {
            f32x4 acc[4] = {{0,0,0,0},{0,0,0,0},{0,0,0,0},{0,0,0,0}};
            #pragma unroll
            for (int s = 0; s < 2; s++) {
                bf16x8 xv = __builtin_bit_cast(bf16x8, Xf[u * 2 + s]);
                #pragma unroll
                for (int fa = 0; fa < 4; fa++)
                    acc[fa] = __builtin_amdgcn_mfma_f32_16x16x32_bf16(Wf[s][fa], xv, acc[fa], 0, 0, 0);
            }
            float* orow = out + ((size_t)t * 64 + u * 16 + m) * 64;
            #pragma unroll
            for (int fa = 0; fa < 4; fa++) {
                f32x4 o;
                #pragma unroll
                for (int r = 0; r < 4; r++) {
                    float x = fmaxf(acc[fa][r] + bias4[fa][r], 0.f);
                    o[r] = fmaf(a34[fa][r], x, c34[fa][r]);
                }
                *(f32x4*)(orow + fa * 16 + quad * 4) = o;   // 16B direct store
            }
        }
    }
    (void)sSum; (void)sSq;
}

extern "C" void kernel_launch(void* const* d_in, const int* in_sizes, int n_in,
                              void* d_out, int out_size, void* d_ws, size_t ws_size,
                              hipStream_t stream)
{
    const float* src  = (const float*)d_in[0];
    const float* dst  = (const float*)d_in[1];
    const float* edg  = (const float*)d_in[2];
    const float* gat  = (const float*)d_in[3];
    const int*   batch= (const int*)d_in[4];
    const float* W1 = (const float*)d_in[5];
    const float* b1 = (const float*)d_in[6];
    const float* W2 = (const float*)d_in[7];
    const float* b2 = (const float*)d_in[8];
    const float* W3 = (const float*)d_in[9];
    const float* b3 = (const float*)d_in[10];
    const float* g1 = (const float*)d_in[11];
    const float* be1= (const float*)d_in[12];
    const float* g2 = (const float*)d_in[13];
    const float* be2= (const float*)d_in[14];
    const float* g3 = (const float*)d_in[15];
    const float* be3= (const float*)d_in[16];

    const int E = in_sizes[0] / 64;
    const int tiles = E / 64;
    const float invE = 1.0f / (float)E;

    char* ws = (char*)d_ws;
    u16*   w1f = (u16*)(ws + 0);            // 32 KB
    float* st1 = (float*)(ws + 49152);      // 3x128 floats contiguous
    float* st2 = st1 + 128;
    float* st3 = st1 + 256;

    const size_t OFF_H = 65536;
    const size_t HSZ = (size_t)E * 128;     // bf16 [E][64]
    u16 *h1, *h2;
    if (ws_size >= OFF_H + 2 * HSZ) {
        h1 = (u16*)(ws + OFF_H); h2 = (u16*)(ws + OFF_H + HSZ);
    } else {  // h1 borrows d_out (dead before K4 writes out); h2 in ws
        h1 = (u16*)d_out; h2 = (u16*)(ws + OFF_H);
    }

    prep_kernel<<<64, 256, 0, stream>>>(W1, w1f, st1);
    gemm1_kernel<<<2048, 256, 0, stream>>>(src, dst, edg, gat, batch, w1f, b1, h1, st1, tiles);
    gemm_mid_kernel<<<1536, 256, 0, stream>>>(h1, W2, b2, st1, invE, g1, be1, h2, st2, tiles);
    gemm_stats_kernel<<<1536, 256, 0, stream>>>(h2, W3, b3, st2, invE, g2, be2, st3, tiles);
    gemm_out_kernel<<<1536, 256, 0, stream>>>(h2, W3, b3, st2, invE, g2, be2, st3, g3, be3,
                                              (float*)d_out, tiles);
}